// Round 13
// baseline (250.801 us; speedup 1.0000x reference)
//
#include <hip/hip_runtime.h>
#include <hip/hip_fp16.h>
#include <stdint.h>

static constexpr int Bc = 16, Cc = 256, Hc = 56, Wc = 56, Gc = 4;
static constexpr int HWc = Hc * Wc;
static constexpr float EPSc = 1e-5f;
static constexpr int ROWP = 72;   // padded abits row: [8 zero | 56 data | 8 zero]
static constexpr int COL0 = 8;

// ---------------------------------------------------------------------------
// Workspace (r4 layout; zero area now unused by conv but kept for layout):
//   ws + 0       : 1024 B zero area
//   ws + 1024    : abits_pad [16][4][56][72] u64 = 2,064,384 B
//   ws + 2065408 : wbits [3][9][256] u64 = 55,296 B
//   ws + 2120704 : scales [768] f32
// ---------------------------------------------------------------------------

__global__ __launch_bounds__(256) void k_prep(
    const float* __restrict__ w, const float* __restrict__ x,
    const float* __restrict__ bias, uint64_t* __restrict__ wbits,
    float* __restrict__ scales, uint64_t* __restrict__ abits,
    uint32_t* __restrict__ zero_area) {
  const int t = threadIdx.x;
  if (blockIdx.x < 192) {
    // ---- weight pack: io = blockIdx*4 + wave ----
    const int io = blockIdx.x * 4 + (t >> 6);
    const int i = io >> 8, o = io & 255;
    const int lane = t & 63;
    const float* wp = w + (size_t)io * 576 + lane * 9;
    float v[9];
    float ssum = 0.f, sabs = 0.f;
#pragma unroll
    for (int k = 0; k < 9; ++k) {
      v[k] = wp[k];
      ssum += v[k];
      sabs += fabsf(v[k]);
    }
#pragma unroll
    for (int off = 32; off > 0; off >>= 1) {
      ssum += __shfl_down(ssum, off);
      sabs += __shfl_down(sabs, off);
    }
    const float mean = __shfl(ssum, 0) * (1.f / 576.f);
    const float scale = __shfl(sabs, 0) * (1.f / 576.f);
#pragma unroll
    for (int k = 0; k < 9; ++k) {
      unsigned long long m = __ballot(v[k] > mean);
      if (lane == 0) wbits[(i * 9 + k) * Cc + o] = m;
    }
    if (lane == 0) scales[io] = scale;
  } else if (blockIdx.x == 192) {
    zero_area[t] = 0;  // 1024 B
  } else {
    // ---- activation pack: block = (b, h, channel-half). Coalesced float4
    // loads -> f32 LDS stage (57-pad: conflict-free) -> per-wave ballot pack.
    __shared__ float sbf[128][57];  // 29,184 B
    const int bid = blockIdx.x - 193;
    const int b = bid / 112;
    const int rem = bid - b * 112;
    const int h = rem >> 1, chh = rem & 1;  // chh: channels [chh*128, +128)
    const float* xb = x + ((size_t)(b * Cc + chh * 128)) * HWc + h * Wc;
#pragma unroll
    for (int k = 0; k < 7; ++k) {
      const int idx = k * 256 + t;  // [0, 1792) = 128 c x 14 q
      const int cl = idx / 14, q = idx - cl * 14;
      const float4 v = *(const float4*)(xb + (size_t)cl * HWc + q * 4);
      const float bc = bias[chh * 128 + cl];
      sbf[cl][q * 4 + 0] = v.x + bc;
      sbf[cl][q * 4 + 1] = v.y + bc;
      sbf[cl][q * 4 + 2] = v.z + bc;
      sbf[cl][q * 4 + 3] = v.w + bc;
    }
    __syncthreads();
    // ballot pack: wave wv -> group-half gl = wv&1, w-range (wv>>1)*28..+28
    const int wv = t >> 6, lane = t & 63;
    const int gl = wv & 1, wb_ = (wv >> 1) * 28;
    uint64_t* rowp =
        abits + (((size_t)b * Gc + chh * 2 + gl) * Hc + h) * ROWP;
#pragma unroll
    for (int i = 0; i < 28; ++i) {
      const int ww = wb_ + i;
      const unsigned long long m = __ballot(sbf[gl * 64 + lane][ww] > 0.f);
      if (lane == 0) rowp[COL0 + ww] = m;
    }
    // zero pads: 2 groups x 16 words (k in [0,8) U [64,72))
    if (t < 32) {
      const int glp = t >> 4, kk = t & 15;
      const int k = (kk < 8) ? kk : (56 + kk);
      abits[(((size_t)b * Gc + chh * 2 + glp) * Hc + h) * ROWP + k] = 0;
    }
  }
}

// ---------------------------------------------------------------------------
// Conv data path (r13): all needed abits rows staged once per block into LDS
// (zero-filled for out-of-range h) -> inner loop reads wave-uniform
// ds_read_b64 broadcasts with immediate offsets. Replaces the per-chunk
// s_load/global_load groups (+64-bit addressing) that dominated r11/r12's
// 9.7k VALU-issue slots per thread. Correction math unchanged:
//   B(w) = 576 - Zrow - (w<D)?ZL:0 - (w>=56-D)?ZR:0;  dot = B - 2*sum popc
// Staged rows per group, index rid: 0:h-5 1:h-3 2:h-1 3:h 4:h+1 5:h+3 6:h+5.
// Staged cols: w in [W0-6, W0+34)  (all reads lie in [W0-5, W0+33)).
// ---------------------------------------------------------------------------
static constexpr int NCH = 7;    // chunk width
static constexpr int WH = 28;    // half-row width
static constexpr int TSH = 30;   // padded out_tile stride (halfs)
static constexpr int SROW = 40;  // staged row width (u64 words)

template <int D>
struct Branch {
  uint64_t wgt[9];
  int BM, ZL, ZR;
  float sc, cbm1, al;
  static constexpr int RID0 = 3 - (D + 1) / 2;  // D=1->2, D=3->1, D=5->0
  static constexpr int RID2 = 3 + (D + 1) / 2;  // D=1->4, D=3->5, D=5->6

  __device__ __forceinline__ void init(const uint64_t* __restrict__ wb, int h,
                                       float sc_, float cbm1_, float al_) {
    sc = sc_; cbm1 = cbm1_; al = al_;
    int z[9];
#pragma unroll
    for (int k = 0; k < 9; ++k) {
      wgt[k] = wb[k * Cc];
      z[k] = 64 - 2 * (int)__builtin_popcountll(wgt[k]);
    }
    const bool v0 = (h - D >= 0), v2 = (h + D < Hc);
    const int Zrow = (v0 ? 0 : (z[0] + z[1] + z[2])) +
                     (v2 ? 0 : (z[6] + z[7] + z[8]));
    BM = 576 - Zrow;
    ZL = (v0 ? z[0] : 0) + z[3] + (v2 ? z[6] : 0);
    ZR = (v0 ? z[2] : 0) + z[5] + (v2 ? z[8] : 0);
  }

  // all 3 kh rows from the staged LDS window; cbase = ch*7 + 6
  __device__ __forceinline__ void accum(const uint64_t (*sg)[SROW], int cbase,
                                        int acc[NCH]) const {
#pragma unroll
    for (int kh = 0; kh < 3; ++kh) {
      const uint64_t* rp =
          (kh == 0) ? sg[RID0] : ((kh == 1) ? sg[3] : sg[RID2]);
      uint64_t seg[NCH + 2 * D];
#pragma unroll
      for (int j = 0; j < NCH + 2 * D; ++j) seg[j] = rp[cbase - D + j];
#pragma unroll
      for (int ww = 0; ww < NCH; ++ww) {
#pragma unroll
        for (int kw = 0; kw < 3; ++kw)
          acc[ww] +=
              (int)__builtin_popcountll(wgt[kh * 3 + kw] ^ seg[ww + D * kw]);
      }
    }
  }

  __device__ __forceinline__ void epi_int(const int acc[NCH],
                                          float outf[NCH]) const {
#pragma unroll
    for (int ww = 0; ww < NCH; ++ww) {
      const float y0 = fmaf(sc, (float)(BM - 2 * acc[ww]), cbm1);
      outf[ww] += fmaxf(y0, 0.f) + al * fminf(y0, 0.f);
    }
  }

  __device__ __forceinline__ void epi_edge(int w0, const int acc[NCH],
                                           float outf[NCH]) const {
#pragma unroll
    for (int ww = 0; ww < NCH; ++ww) {
      const int w = w0 + ww;
      const int B = BM - ((w < D) ? ZL : 0) - ((w >= Wc - D) ? ZR : 0);
      const float y0 = fmaf(sc, (float)(B - 2 * acc[ww]), cbm1);
      outf[ww] += fmaxf(y0, 0.f) + al * fminf(y0, 0.f);
    }
  }
};

// ---------------------------------------------------------------------------
// K2: fused conv(3 branches)+bias+RPReLU+sum+LayerNorm. Block = (b,h,half).
// XCD-chunked bijective swizzle (1792 = 8*224; r8/r11-proven FETCH cut).
// ---------------------------------------------------------------------------
__global__ __launch_bounds__(256, 4) void k_conv_ln(
    const uint64_t* __restrict__ abits, const uint64_t* __restrict__ wbits,
    const float* __restrict__ scales, const float* __restrict__ cb,
    const float* __restrict__ mv1, const float* __restrict__ al,
    const float* __restrict__ mv2, const float* __restrict__ gamma,
    const float* __restrict__ beta, float* __restrict__ out) {
  __shared__ uint64_t srows[Gc][7][SROW];  // 8,960 B staged abits windows
  __shared__ __half out_tile[Cc * TSH];    // 15,360 B
  __shared__ float redu[4][WH], redq[4][WH];
  __shared__ float mstat[WH], rstat[WH];

  const int bid0 = blockIdx.x;                     // hw id (round-robin XCD)
  const int swz = (bid0 & 7) * 224 + (bid0 >> 3);  // XCD-chunked, bijective
  const int wh = swz & 1;   // which half of the row
  const int bh = swz >> 1;  // b*56 + h
  const int b = bh / Hc, h = bh % Hc;
  const int W0 = wh * WH;
  const int t = threadIdx.x;  // output channel
  const int gu = __builtin_amdgcn_readfirstlane(t >> 6);

  // ---- stage abits windows: 4 groups x 7 rows x 40 words, zero-filled OOB
  for (int idx = t; idx < Gc * 7 * SROW; idx += 256) {
    const int g = idx / (7 * SROW);
    const int rem2 = idx - g * (7 * SROW);
    const int r7 = rem2 / SROW;
    const int cw = rem2 - r7 * SROW;
    const int off = (r7 < 3) ? (2 * r7 - 5) : ((r7 == 3) ? 0 : (2 * r7 - 7));
    const int hr = h + off;
    uint64_t v = 0;
    if (hr >= 0 && hr < Hc)
      v = abits[(((size_t)b * Gc + g) * Hc + hr) * ROWP + COL0 + (W0 - 6) +
                cw];
    srows[g][r7][cw] = v;
  }

  Branch<1> b0; Branch<3> b1; Branch<5> b2;
  b0.init(wbits + 0 * 9 * Cc + t, h, scales[0 * Cc + t],
          cb[0 * Cc + t] - mv1[0 * Cc + t], al[0 * Cc + t]);
  b1.init(wbits + 1 * 9 * Cc + t, h, scales[1 * Cc + t],
          cb[1 * Cc + t] - mv1[1 * Cc + t], al[1 * Cc + t]);
  b2.init(wbits + 2 * 9 * Cc + t, h, scales[2 * Cc + t],
          cb[2 * Cc + t] - mv1[2 * Cc + t], al[2 * Cc + t]);
  const float m2sum = mv2[0 * Cc + t] + mv2[1 * Cc + t] + mv2[2 * Cc + t];

  __syncthreads();
  const uint64_t (*sg)[SROW] = srows[gu];  // wave-uniform group window

#pragma unroll 1
  for (int ch = 0; ch < 4; ++ch) {  // runtime loop: keeps live ranges small
    const int w0 = W0 + ch * NCH;
    const int cbase = ch * NCH + 6;  // staged-col of w0
    const bool interior = (w0 >= 5) && (w0 <= Wc - NCH - 5);  // all B == BM
    float outf[NCH];
#pragma unroll
    for (int ww = 0; ww < NCH; ++ww) outf[ww] = m2sum;
    {
      int acc[NCH] = {};
      b0.accum(sg, cbase, acc);
      if (interior) b0.epi_int(acc, outf); else b0.epi_edge(w0, acc, outf);
    }
    {
      int acc[NCH] = {};
      b1.accum(sg, cbase, acc);
      if (interior) b1.epi_int(acc, outf); else b1.epi_edge(w0, acc, outf);
    }
    {
      int acc[NCH] = {};
      b2.accum(sg, cbase, acc);
      if (interior) b2.epi_int(acc, outf); else b2.epi_edge(w0, acc, outf);
    }
#pragma unroll
    for (int ww = 0; ww < NCH; ++ww)
      out_tile[t * TSH + ch * NCH + ww] = __float2half(outf[ww]);
  }
  __syncthreads();

  // ---- LN stats (per output column over 256 channels) ----
  if (t < 4 * WH) {
    const int ww = t % WH;
    const int cq = t / WH;
    float s = 0.f, sq = 0.f;
#pragma unroll 4
    for (int c = cq * 64; c < cq * 64 + 64; ++c) {
      const float v = __half2float(out_tile[c * TSH + ww]);
      s += v;
      sq = fmaf(v, v, sq);
    }
    redu[cq][ww] = s;
    redq[cq][ww] = sq;
  }
  __syncthreads();
  if (t < WH) {
    const float s = redu[0][t] + redu[1][t] + redu[2][t] + redu[3][t];
    const float sq = redq[0][t] + redq[1][t] + redq[2][t] + redq[3][t];
    const float mean = s * (1.f / 256.f);
    const float var = sq * (1.f / 256.f) - mean * mean;
    mstat[t] = mean;
    rstat[t] = rsqrtf(var + EPSc);
  }
  __syncthreads();

  // ---- normalize + coalesced store ----
  float* base = out + ((size_t)b * Cc * Hc + h) * Wc + W0;
  for (int idx = t; idx < Cc * WH; idx += 256) {
    const int c = idx / WH;
    const int ww = idx - c * WH;
    const float v = __half2float(out_tile[c * TSH + ww]);
    base[(size_t)c * HWc + ww] = (v - mstat[ww]) * rstat[ww] * gamma[c] + beta[c];
  }
}

// ---------------------------------------------------------------------------
extern "C" void kernel_launch(void* const* d_in, const int* in_sizes, int n_in,
                              void* d_out, int out_size, void* d_ws, size_t ws_size,
                              hipStream_t stream) {
  const float* x     = (const float*)d_in[0];
  const float* bias  = (const float*)d_in[1];
  const float* w     = (const float*)d_in[2];
  const float* cb    = (const float*)d_in[3];
  const float* mv1   = (const float*)d_in[4];
  const float* al    = (const float*)d_in[5];
  const float* mv2   = (const float*)d_in[6];
  const float* gamma = (const float*)d_in[7];
  const float* beta  = (const float*)d_in[8];
  float* out = (float*)d_out;

  uint8_t* ws = (uint8_t*)d_ws;
  uint32_t* zero_area = (uint32_t*)ws;
  uint64_t* abits = (uint64_t*)(ws + 1024);
  const size_t abits_bytes = (size_t)Bc * Gc * Hc * ROWP * 8;  // 2,064,384
  uint64_t* wbits = (uint64_t*)(ws + 1024 + abits_bytes);
  float* scales = (float*)(ws + 1024 + abits_bytes + 6912 * 8);

  hipLaunchKernelGGL(k_prep, dim3(192 + 1 + Bc * Hc * 2), dim3(256), 0, stream,
                     w, x, bias, wbits, scales, abits, zero_area);
  hipLaunchKernelGGL(k_conv_ln, dim3(Bc * Hc * 2), dim3(256), 0, stream,
                     abits, wbits, scales, cb, mv1, al, mv2, gamma, beta,
                     out);
}

// Round 15
// 176.941 us; speedup vs baseline: 1.4174x; 1.4174x over previous
//
#include <hip/hip_runtime.h>
#include <hip/hip_fp16.h>
#include <stdint.h>

static constexpr int Bc = 16, Cc = 256, Hc = 56, Wc = 56, Gc = 4;
static constexpr int HWc = Hc * Wc;
static constexpr float EPSc = 1e-5f;
static constexpr int ROWP = 72;   // padded abits row: [8 zero | 56 data | 8 zero]
static constexpr int COL0 = 8;

// ---------------------------------------------------------------------------
// Workspace (r4 layout):
//   ws + 0       : 1024 B zero area (zrowp = ws + 8 u64)
//   ws + 1024    : abits_pad [16][4][56][72] u64 = 2,064,384 B
//   ws + 2065408 : wbits [3][9][256] u64 = 55,296 B
//   ws + 2120704 : scales [768] f32
// ---------------------------------------------------------------------------

static constexpr int SBS2 = 132;  // sign-byte LDS row stride (128 ch + pad)

__global__ __launch_bounds__(256) void k_prep(
    const float* __restrict__ w, const float* __restrict__ x,
    const float* __restrict__ bias, uint64_t* __restrict__ wbits,
    float* __restrict__ scales, uint64_t* __restrict__ abits,
    uint32_t* __restrict__ zero_area) {
  const int t = threadIdx.x;
  if (blockIdx.x < 192) {
    // ---- weight pack: io = blockIdx*4 + wave ----
    const int io = blockIdx.x * 4 + (t >> 6);
    const int i = io >> 8, o = io & 255;
    const int lane = t & 63;
    const float* wp = w + (size_t)io * 576 + lane * 9;
    float v[9];
    float ssum = 0.f, sabs = 0.f;
#pragma unroll
    for (int k = 0; k < 9; ++k) {
      v[k] = wp[k];
      ssum += v[k];
      sabs += fabsf(v[k]);
    }
#pragma unroll
    for (int off = 32; off > 0; off >>= 1) {
      ssum += __shfl_down(ssum, off);
      sabs += __shfl_down(sabs, off);
    }
    const float mean = __shfl(ssum, 0) * (1.f / 576.f);
    const float scale = __shfl(sabs, 0) * (1.f / 576.f);
#pragma unroll
    for (int k = 0; k < 9; ++k) {
      unsigned long long m = __ballot(v[k] > mean);
      if (lane == 0) wbits[(i * 9 + k) * Cc + o] = m;
    }
    if (lane == 0) scales[io] = scale;
  } else if (blockIdx.x == 192) {
    zero_area[t] = 0;  // 1024 B
  } else {
    // ---- activation pack: block = (b, h, channel-half). 1792 blocks.
    // Coalesced float4 loads + LDS byte transpose + nibble bit-pack.
    __shared__ uint8_t sb[Wc * SBS2];  // [w][c_local], 7392 B
    const int bid = blockIdx.x - 193;
    const int b = bid / 112;
    const int rem = bid - b * 112;
    const int h = rem >> 1, chh = rem & 1;  // chh: channels [chh*128, +128)
    const float* xb = x + ((size_t)(b * Cc + chh * 128)) * HWc + h * Wc;
#pragma unroll
    for (int k = 0; k < 7; ++k) {
      const int idx = k * 256 + t;  // [0, 1792) = 128 c x 14 q
      const int cl = idx / 14, q = idx - cl * 14;
      const float4 v = *(const float4*)(xb + (size_t)cl * HWc + q * 4);
      const float bc = bias[chh * 128 + cl];
      sb[(q * 4 + 0) * SBS2 + cl] = (v.x + bc > 0.f);
      sb[(q * 4 + 1) * SBS2 + cl] = (v.y + bc > 0.f);
      sb[(q * 4 + 2) * SBS2 + cl] = (v.z + bc > 0.f);
      sb[(q * 4 + 3) * SBS2 + cl] = (v.w + bc > 0.f);
    }
    __syncthreads();
    // pack: 2 local groups x 72 padded words
    if (t < 2 * ROWP) {
      const int gl = t / ROWP, k = t - gl * ROWP;
      uint64_t word = 0;
      if (k >= COL0 && k < COL0 + Wc) {
        const int ww = k - COL0;
        const uint32_t* p = (const uint32_t*)(sb + ww * SBS2 + gl * 64);
        uint64_t acc = 0;
#pragma unroll
        for (int dw = 0; dw < 16; ++dw) {
          const uint32_t d = p[dw];
          const uint32_t nib = (d | (d >> 7) | (d >> 14) | (d >> 21)) & 0xF;
          acc |= (uint64_t)nib << (4 * dw);
        }
        word = acc;
      }
      const int g = chh * 2 + gl;
      abits[(((size_t)b * Gc + g) * Hc + h) * ROWP + k] = word;
    }
  }
}

// ---------------------------------------------------------------------------
// Per-branch conv state (r4-proven popcount scheme). Row pointers wave-
// uniform; segments -> SGPRs (r13 lesson: LDS staging moves them to VGPRs
// and spills — never do that). Row h (kh=1) SHARED across branches via
// smid[17]. Exact integer correction:
//   B(w) = 576 - Zrow - (w<D)?ZL:0 - (w>=56-D)?ZR:0;  dot = B - 2*sum popc
// ---------------------------------------------------------------------------
static constexpr int NCH = 7;   // chunk width
static constexpr int WH = 28;   // half-row width
static constexpr int TSH = 30;  // padded out_tile stride (halfs)

template <int D>
struct Branch {
  uint64_t wgt[9];
  const uint64_t *r0, *r2;  // kh=0 / kh=2 rows (col 0)
  int BM, ZL, ZR;
  float sc, cbm1, al;

  __device__ __forceinline__ void init(const uint64_t* __restrict__ wb,
                                       const uint64_t* rowbase,  // col0,row0
                                       const uint64_t* zrowp, int h,
                                       float sc_, float cbm1_, float al_) {
    sc = sc_; cbm1 = cbm1_; al = al_;
    int z[9];
#pragma unroll
    for (int k = 0; k < 9; ++k) {
      wgt[k] = wb[k * Cc];
      z[k] = 64 - 2 * (int)__builtin_popcountll(wgt[k]);
    }
    const bool v0 = (h - D >= 0), v2 = (h + D < Hc);
    r0 = v0 ? (rowbase + (size_t)(h - D) * ROWP) : zrowp;
    r2 = v2 ? (rowbase + (size_t)(h + D) * ROWP) : zrowp;
    const int Zrow = (v0 ? 0 : (z[0] + z[1] + z[2])) +
                     (v2 ? 0 : (z[6] + z[7] + z[8]));
    BM = 576 - Zrow;
    ZL = (v0 ? z[0] : 0) + z[3] + (v2 ? z[6] : 0);
    ZR = (v0 ? z[2] : 0) + z[5] + (v2 ? z[8] : 0);
  }

  // kh = 0, 2 rows
  __device__ __forceinline__ void accum_edge(int w0, int acc[NCH]) const {
#pragma unroll
    for (int kh = 0; kh < 3; kh += 2) {
      const uint64_t* rp = (kh == 0) ? r0 : r2;
      uint64_t seg[NCH + 2 * D];  // wave-uniform -> SGPRs
#pragma unroll
      for (int j = 0; j < NCH + 2 * D; ++j) seg[j] = rp[w0 - D + j];
#pragma unroll
      for (int ww = 0; ww < NCH; ++ww) {
#pragma unroll
        for (int kw = 0; kw < 3; ++kw)
          acc[ww] +=
              (int)__builtin_popcountll(wgt[kh * 3 + kw] ^ seg[ww + D * kw]);
      }
    }
  }

  // kh = 1 from shared row-h segment smid[j] = r1[w0 - 5 + j]
  __device__ __forceinline__ void accum_mid(const uint64_t* smid,
                                            int acc[NCH]) const {
#pragma unroll
    for (int ww = 0; ww < NCH; ++ww) {
#pragma unroll
      for (int kw = 0; kw < 3; ++kw)
        acc[ww] += (int)__builtin_popcountll(
            wgt[3 + kw] ^ smid[ww + 5 - D + D * kw]);
    }
  }

  // interior chunk: no W-edge corrections (B = BM for all outputs)
  __device__ __forceinline__ void epi_int(const int acc[NCH],
                                          float outf[NCH]) const {
#pragma unroll
    for (int ww = 0; ww < NCH; ++ww) {
      const float y0 = fmaf(sc, (float)(BM - 2 * acc[ww]), cbm1);
      outf[ww] += fmaxf(y0, 0.f) + al * fminf(y0, 0.f);
    }
  }

  __device__ __forceinline__ void epi_edge(int w0, const int acc[NCH],
                                           float outf[NCH]) const {
#pragma unroll
    for (int ww = 0; ww < NCH; ++ww) {
      const int w = w0 + ww;
      const int B = BM - ((w < D) ? ZL : 0) - ((w >= Wc - D) ? ZR : 0);
      const float y0 = fmaf(sc, (float)(B - 2 * acc[ww]), cbm1);
      outf[ww] += fmaxf(y0, 0.f) + al * fminf(y0, 0.f);
    }
  }
};

// ---------------------------------------------------------------------------
// K2: fused conv(3 branches)+bias+RPReLU+sum+LayerNorm. Block = (b,h,half):
// 28 output columns x 256 channels. Thread = output channel.
// XCD-chunked bijective swizzle (1792 = 8*224): each XCD owns 224 consecutive
// half-row blocks = 2 images of abits slice -> L2-resident (r8/r11-proven:
// FETCH 16.3 -> 7.6 MB).
// ---------------------------------------------------------------------------
__global__ __launch_bounds__(256, 4) void k_conv_ln(
    const uint64_t* __restrict__ abits, const uint64_t* __restrict__ zrowp,
    const uint64_t* __restrict__ wbits, const float* __restrict__ scales,
    const float* __restrict__ cb, const float* __restrict__ mv1,
    const float* __restrict__ al, const float* __restrict__ mv2,
    const float* __restrict__ gamma, const float* __restrict__ beta,
    float* __restrict__ out) {
  __shared__ __half out_tile[Cc * TSH];
  __shared__ float redu[4][WH], redq[4][WH];
  __shared__ float mstat[WH], rstat[WH];

  const int bid0 = blockIdx.x;                     // hw id (round-robin XCD)
  const int swz = (bid0 & 7) * 224 + (bid0 >> 3);  // XCD-chunked, bijective
  const int wh = swz & 1;   // which half of the row
  const int bh = swz >> 1;  // b*56 + h
  const int b = bh / Hc, h = bh % Hc;
  const int W0 = wh * WH;
  const int t = threadIdx.x;  // output channel
  const int gu = __builtin_amdgcn_readfirstlane(t >> 6);

  const uint64_t* rowbase = abits + ((size_t)b * Gc + gu) * Hc * ROWP + COL0;
  const uint64_t* r1 = rowbase + (size_t)h * ROWP;  // mid row, always valid

  Branch<1> b0; Branch<3> b1; Branch<5> b2;
  b0.init(wbits + 0 * 9 * Cc + t, rowbase, zrowp, h, scales[0 * Cc + t],
          cb[0 * Cc + t] - mv1[0 * Cc + t], al[0 * Cc + t]);
  b1.init(wbits + 1 * 9 * Cc + t, rowbase, zrowp, h, scales[1 * Cc + t],
          cb[1 * Cc + t] - mv1[1 * Cc + t], al[1 * Cc + t]);
  b2.init(wbits + 2 * 9 * Cc + t, rowbase, zrowp, h, scales[2 * Cc + t],
          cb[2 * Cc + t] - mv1[2 * Cc + t], al[2 * Cc + t]);
  const float m2sum = mv2[0 * Cc + t] + mv2[1 * Cc + t] + mv2[2 * Cc + t];

#pragma unroll 1
  for (int ch = 0; ch < 4; ++ch) {  // runtime loop: keeps live ranges small
    const int w0 = W0 + ch * NCH;
    // shared row-h segment, span [w0-5, w0+12): covers kh=1 of all branches
    uint64_t smid[17];
#pragma unroll
    for (int j = 0; j < 17; ++j) smid[j] = r1[w0 - 5 + j];
    const bool interior = (w0 >= 5) && (w0 <= Wc - NCH - 5);  // all B == BM
    float outf[NCH];
#pragma unroll
    for (int ww = 0; ww < NCH; ++ww) outf[ww] = m2sum;
    {
      int acc[NCH] = {};
      b0.accum_edge(w0, acc); b0.accum_mid(smid, acc);
      if (interior) b0.epi_int(acc, outf); else b0.epi_edge(w0, acc, outf);
    }
    {
      int acc[NCH] = {};
      b1.accum_edge(w0, acc); b1.accum_mid(smid, acc);
      if (interior) b1.epi_int(acc, outf); else b1.epi_edge(w0, acc, outf);
    }
    {
      int acc[NCH] = {};
      b2.accum_edge(w0, acc); b2.accum_mid(smid, acc);
      if (interior) b2.epi_int(acc, outf); else b2.epi_edge(w0, acc, outf);
    }
#pragma unroll
    for (int ww = 0; ww < NCH; ++ww)
      out_tile[t * TSH + ch * NCH + ww] = __float2half(outf[ww]);
  }
  __syncthreads();

  // ---- LN stats (per output column over 256 channels) ----
  if (t < 4 * WH) {
    const int ww = t % WH;
    const int cq = t / WH;
    float s = 0.f, sq = 0.f;
#pragma unroll 4
    for (int c = cq * 64; c < cq * 64 + 64; ++c) {
      const float v = __half2float(out_tile[c * TSH + ww]);
      s += v;
      sq = fmaf(v, v, sq);
    }
    redu[cq][ww] = s;
    redq[cq][ww] = sq;
  }
  __syncthreads();
  if (t < WH) {
    const float s = redu[0][t] + redu[1][t] + redu[2][t] + redu[3][t];
    const float sq = redq[0][t] + redq[1][t] + redq[2][t] + redq[3][t];
    const float mean = s * (1.f / 256.f);
    const float var = sq * (1.f / 256.f) - mean * mean;
    mstat[t] = mean;
    rstat[t] = rsqrtf(var + EPSc);
  }
  __syncthreads();

  // ---- normalize + coalesced store ----
  float* base = out + ((size_t)b * Cc * Hc + h) * Wc + W0;
  for (int idx = t; idx < Cc * WH; idx += 256) {
    const int c = idx / WH;
    const int ww = idx - c * WH;
    const float v = __half2float(out_tile[c * TSH + ww]);
    base[(size_t)c * HWc + ww] = (v - mstat[ww]) * rstat[ww] * gamma[c] + beta[c];
  }
}

// ---------------------------------------------------------------------------
extern "C" void kernel_launch(void* const* d_in, const int* in_sizes, int n_in,
                              void* d_out, int out_size, void* d_ws, size_t ws_size,
                              hipStream_t stream) {
  const float* x     = (const float*)d_in[0];
  const float* bias  = (const float*)d_in[1];
  const float* w     = (const float*)d_in[2];
  const float* cb    = (const float*)d_in[3];
  const float* mv1   = (const float*)d_in[4];
  const float* al    = (const float*)d_in[5];
  const float* mv2   = (const float*)d_in[6];
  const float* gamma = (const float*)d_in[7];
  const float* beta  = (const float*)d_in[8];
  float* out = (float*)d_out;

  uint8_t* ws = (uint8_t*)d_ws;
  uint32_t* zero_area = (uint32_t*)ws;
  const uint64_t* zrowp = (const uint64_t*)ws + COL0;
  uint64_t* abits = (uint64_t*)(ws + 1024);
  const size_t abits_bytes = (size_t)Bc * Gc * Hc * ROWP * 8;  // 2,064,384
  uint64_t* wbits = (uint64_t*)(ws + 1024 + abits_bytes);
  float* scales = (float*)(ws + 1024 + abits_bytes + 6912 * 8);

  hipLaunchKernelGGL(k_prep, dim3(192 + 1 + Bc * Hc * 2), dim3(256), 0, stream,
                     w, x, bias, wbits, scales, abits, zero_area);
  hipLaunchKernelGGL(k_conv_ln, dim3(Bc * Hc * 2), dim3(256), 0, stream,
                     abits, zrowp, wbits, scales, cb, mv1, al, mv2, gamma, beta,
                     out);
}